// Round 2
// baseline (458.356 us; speedup 1.0000x reference)
//
#include <hip/hip_runtime.h>
#include <hip/hip_bf16.h>
#include <stdint.h>

#define T_DIM 2048
#define B_DIM 4
#define E_DIM 1024
#define H_DIM 16
#define EHD 64
#define L2E 1.4426950408889634f

typedef __attribute__((ext_vector_type(8))) short bf16x8;
typedef __attribute__((ext_vector_type(4))) float f32x4;

__device__ __forceinline__ unsigned short f2bf(float x) {
  unsigned int u = __builtin_bit_cast(unsigned int, x);
  u += 0x7fffu + ((u >> 16) & 1u);
  return (unsigned short)(u >> 16);
}

__device__ __forceinline__ void gload16(const void* g, void* l) {
  __builtin_amdgcn_global_load_lds(
      (const __attribute__((address_space(1))) void*)g,
      (__attribute__((address_space(3))) void*)l, 16, 0, 0);
}

// ---------------- fp32 -> bf16 ----------------
__global__ __launch_bounds__(256) void cvt_kernel(const float4* __restrict__ in,
                                                  uint2* __restrict__ out, int n4) {
  int i = blockIdx.x * 256 + threadIdx.x;
  int stride = gridDim.x * 256;
  for (; i < n4; i += stride) {
    float4 f = in[i];
    uint2 o;
    o.x = (unsigned)f2bf(f.x) | ((unsigned)f2bf(f.y) << 16);
    o.y = (unsigned)f2bf(f.z) | ((unsigned)f2bf(f.w) << 16);
    out[i] = o;
  }
}

// ---------------- 128x128 bf16 NT GEMM (m97 structure) ----------------
// MODE 0: QKV projection. A selected per N-third (query/key/value), bias=b_qkv,
//         scatter bf16 C into QKV[which][b][h][t][d].
// MODE 1: out projection. bias=b_out, write FP32 out[(t*B+b)*E + n]
//         (reference output dtype is float32 -> d_out is float*).
template <int MODE>
__global__ __launch_bounds__(256) void gemm_kernel(
    const unsigned short* __restrict__ Abase,
    const unsigned short* __restrict__ Bt,
    const float* __restrict__ bias,
    void* __restrict__ outv, int K) {
  __shared__ alignas(16) short As[128 * 32];
  __shared__ alignas(16) short Bs[128 * 32];
  const int tid = threadIdx.x;
  const int lane = tid & 63, wave = tid >> 6;
  const int m0 = blockIdx.x * 128, n0 = blockIdx.y * 128;
  const int wr = wave >> 1, wc = wave & 1;
  const int lrow = lane & 15, lgrp = lane >> 4;

  const unsigned short* A = Abase;
  if (MODE == 0) A += (size_t)(n0 >> 10) * (8192u * 1024u);

  f32x4 acc[4][4];
#pragma unroll
  for (int m = 0; m < 4; ++m)
#pragma unroll
    for (int n = 0; n < 4; ++n) acc[m][n] = (f32x4){0.f, 0.f, 0.f, 0.f};

  const int srow = wave * 16 + (lane >> 2);  // staging row (per issue of 64 rows)
  const int scol = (lane & 3) * 8;           // staging col (elements)
  short* lA0 = As + wave * 16 * 32;
  short* lA1 = As + (64 + wave * 16) * 32;
  short* lB0 = Bs + wave * 16 * 32;
  short* lB1 = Bs + (64 + wave * 16) * 32;

  for (int k0 = 0; k0 < K; k0 += 32) {
    const unsigned short* ga = A + (size_t)(m0 + srow) * K + k0 + scol;
    const unsigned short* gb = Bt + (size_t)(n0 + srow) * K + k0 + scol;
    gload16(ga, lA0);
    gload16(ga + (size_t)64 * K, lA1);
    gload16(gb, lB0);
    gload16(gb + (size_t)64 * K, lB1);
    __syncthreads();
    const short* pa = As + (wr * 64 + lrow) * 32 + lgrp * 8;
    const short* pb = Bs + (wc * 64 + lrow) * 32 + lgrp * 8;
    bf16x8 a[4], b[4];
#pragma unroll
    for (int m = 0; m < 4; ++m) a[m] = *(const bf16x8*)(pa + m * 512);
#pragma unroll
    for (int n = 0; n < 4; ++n) b[n] = *(const bf16x8*)(pb + n * 512);
#pragma unroll
    for (int m = 0; m < 4; ++m)
#pragma unroll
      for (int n = 0; n < 4; ++n)
        acc[m][n] = __builtin_amdgcn_mfma_f32_16x16x32_bf16(a[m], b[n], acc[m][n], 0, 0, 0);
    __syncthreads();
  }

#pragma unroll
  for (int n = 0; n < 4; ++n) {
    const int gn = n0 + wc * 64 + n * 16 + lrow;
    const float bv = bias[gn];
    if (MODE == 0) {
      unsigned short* out = (unsigned short*)outv;
      const int which = gn >> 10;
      const int e = gn & 1023;
      const int hh = e >> 6, dd = e & 63;
      unsigned short* op =
          out + ((size_t)which * B_DIM * H_DIM + hh) * (size_t)(T_DIM * EHD) + dd;
#pragma unroll
      for (int m = 0; m < 4; ++m)
#pragma unroll
        for (int r = 0; r < 4; ++r) {
          const int gm = m0 + wr * 64 + m * 16 + lgrp * 4 + r;
          const int t = gm >> 2, bb = gm & 3;  // row index is t*B + b
          op[(size_t)bb * H_DIM * (T_DIM * EHD) + (size_t)t * EHD] =
              f2bf(acc[m][n][r] + bv);
        }
    } else {
      float* out = (float*)outv;
#pragma unroll
      for (int m = 0; m < 4; ++m)
#pragma unroll
        for (int r = 0; r < 4; ++r) {
          const int gm = m0 + wr * 64 + m * 16 + lgrp * 4 + r;  // row = b*T + t
          const int bb = gm >> 11, t = gm & 2047;
          out[((size_t)t * B_DIM + bb) * E_DIM + gn] = acc[m][n][r] + bv;
        }
    }
  }
}

// ---------------- V transpose: [bh][t][d] -> [bh][d][t] ----------------
__global__ __launch_bounds__(256) void transpose_v(const unsigned short* __restrict__ V,
                                                   unsigned short* __restrict__ Vt) {
  __shared__ unsigned short tile[64][68];
  const int bh = blockIdx.y, t0 = blockIdx.x * 64, tid = threadIdx.x;
  const size_t ib = (size_t)bh * (T_DIM * EHD);
  for (int i = tid; i < 1024; i += 256) {
    const int r = i >> 4, c = (i & 15) * 4;
    *(uint2*)&tile[r][c] = *(const uint2*)(V + ib + (size_t)(t0 + r) * EHD + c);
  }
  __syncthreads();
  for (int i = tid; i < 1024; i += 256) {
    const int d = i >> 4, c = (i & 15) * 4;
    uint2 o;
    o.x = (unsigned)tile[c + 0][d] | ((unsigned)tile[c + 1][d] << 16);
    o.y = (unsigned)tile[c + 2][d] | ((unsigned)tile[c + 3][d] << 16);
    *(uint2*)(Vt + (size_t)bh * (EHD * T_DIM) + (size_t)d * T_DIM + t0 + c) = o;
  }
}

// ---------------- flash attention with multiplicative mask ----------------
// grid (T/64, B*H), 256 threads = 4 waves x 16 q-rows. KV tile = 64.
__global__ __launch_bounds__(256) void attn_kernel(
    const unsigned short* __restrict__ Qm, const unsigned short* __restrict__ Km,
    const unsigned short* __restrict__ Vtm, const float* __restrict__ mask,
    unsigned short* __restrict__ ctx) {
  __shared__ alignas(16) short Ks[64 * 64];
  __shared__ alignas(16) short Vs[64 * 64];
  __shared__ alignas(16) short Pl[4][16 * 72];  // padded: kills 16-way bank conflict
  const int tid = threadIdx.x, lane = tid & 63, wave = tid >> 6;
  const int lrow = lane & 15, lgrp = lane >> 4;
  const int bh = blockIdx.y;
  const int b = bh >> 4, h = bh & 15;
  const int q0 = blockIdx.x * 64;

  const size_t base = (size_t)bh * (T_DIM * EHD);
  const unsigned short* qp =
      Qm + base + (size_t)(q0 + wave * 16 + lrow) * EHD + lgrp * 8;
  const bf16x8 qf0 = *(const bf16x8*)qp;
  const bf16x8 qf1 = *(const bf16x8*)(qp + 32);

  f32x4 oacc[4];
#pragma unroll
  for (int n = 0; n < 4; ++n) oacc[n] = (f32x4){0.f, 0.f, 0.f, 0.f};
  float mrun[4], lrun[4];
#pragma unroll
  for (int r = 0; r < 4; ++r) { mrun[r] = -1e30f; lrun[r] = 0.f; }

  const float* mrow = mask + (size_t)(q0 + wave * 16 + lgrp * 4) * T_DIM;
  short* pl = Pl[wave];

  for (int kv0 = 0; kv0 < T_DIM; kv0 += 64) {
#pragma unroll
    for (int i = 0; i < 2; ++i) {
      const int r = i * 32 + wave * 8;
      gload16(Km + base + (size_t)(kv0 + r + (lane >> 3)) * EHD + (lane & 7) * 8,
              Ks + r * 64);
      gload16(Vtm + (size_t)bh * (EHD * T_DIM) + (size_t)(r + (lane >> 3)) * T_DIM +
                  kv0 + (lane & 7) * 8,
              Vs + r * 64);
    }
    __syncthreads();

    float sv[4][4];
#pragma unroll
    for (int n = 0; n < 4; ++n) {
      const short* kp = Ks + (n * 16 + lrow) * 64 + lgrp * 8;
      const bf16x8 kf0 = *(const bf16x8*)kp;
      const bf16x8 kf1 = *(const bf16x8*)(kp + 32);
      f32x4 s = (f32x4){0.f, 0.f, 0.f, 0.f};
      s = __builtin_amdgcn_mfma_f32_16x16x32_bf16(qf0, kf0, s, 0, 0, 0);
      s = __builtin_amdgcn_mfma_f32_16x16x32_bf16(qf1, kf1, s, 0, 0, 0);
#pragma unroll
      for (int r = 0; r < 4; ++r) {
        const float mval = mrow[(size_t)r * T_DIM + kv0 + n * 16 + lrow];
        sv[n][r] = s[r] * 0.125f * mval;  // scale = 1/sqrt(64), then multiplicative mask
      }
    }

    float rmax[4], corr[4], rsum[4];
#pragma unroll
    for (int r = 0; r < 4; ++r)
      rmax[r] = fmaxf(fmaxf(sv[0][r], sv[1][r]), fmaxf(sv[2][r], sv[3][r]));
#pragma unroll
    for (int d = 1; d < 16; d <<= 1)
#pragma unroll
      for (int r = 0; r < 4; ++r) rmax[r] = fmaxf(rmax[r], __shfl_xor(rmax[r], d));
#pragma unroll
    for (int r = 0; r < 4; ++r) {
      const float mn = fmaxf(mrun[r], rmax[r]);
      corr[r] = exp2f((mrun[r] - mn) * L2E);
      mrun[r] = mn;
      rsum[r] = 0.f;
    }
    unsigned short pb[4][4];
#pragma unroll
    for (int n = 0; n < 4; ++n)
#pragma unroll
      for (int r = 0; r < 4; ++r) {
        const float p = exp2f((sv[n][r] - mrun[r]) * L2E);
        rsum[r] += p;
        pb[n][r] = f2bf(p);
      }
#pragma unroll
    for (int d = 1; d < 16; d <<= 1)
#pragma unroll
      for (int r = 0; r < 4; ++r) rsum[r] += __shfl_xor(rsum[r], d);
#pragma unroll
    for (int r = 0; r < 4; ++r) lrun[r] = lrun[r] * corr[r] + rsum[r];
#pragma unroll
    for (int n = 0; n < 4; ++n)
#pragma unroll
      for (int r = 0; r < 4; ++r) oacc[n][r] *= corr[r];

#pragma unroll
    for (int n = 0; n < 4; ++n)
#pragma unroll
      for (int r = 0; r < 4; ++r)
        pl[(lgrp * 4 + r) * 72 + n * 16 + lrow] = (short)pb[n][r];

#pragma unroll
    for (int kc = 0; kc < 2; ++kc) {
      const bf16x8 pa = *(const bf16x8*)(pl + lrow * 72 + kc * 32 + lgrp * 8);
#pragma unroll
      for (int n = 0; n < 4; ++n) {
        const bf16x8 vf = *(const bf16x8*)(Vs + (n * 16 + lrow) * 64 + kc * 32 + lgrp * 8);
        oacc[n] = __builtin_amdgcn_mfma_f32_16x16x32_bf16(pa, vf, oacc[n], 0, 0, 0);
      }
    }
    __syncthreads();
  }

  float inv[4];
#pragma unroll
  for (int r = 0; r < 4; ++r) inv[r] = 1.f / lrun[r];
#pragma unroll
  for (int n = 0; n < 4; ++n)
#pragma unroll
    for (int r = 0; r < 4; ++r) {
      const size_t row = (size_t)b * T_DIM + q0 + wave * 16 + lgrp * 4 + r;
      ctx[row * E_DIM + h * EHD + n * 16 + lrow] = f2bf(oacc[n][r] * inv[r]);
    }
}

extern "C" void kernel_launch(void* const* d_in, const int* in_sizes, int n_in,
                              void* d_out, int out_size, void* d_ws, size_t ws_size,
                              hipStream_t stream) {
  const float* q    = (const float*)d_in[0];
  const float* k    = (const float*)d_in[1];
  const float* v    = (const float*)d_in[2];
  const float* mask = (const float*)d_in[3];
  const float* wqkv = (const float*)d_in[4];
  const float* bqkv = (const float*)d_in[5];
  const float* wout = (const float*)d_in[6];
  const float* bout = (const float*)d_in[7];

  char* ws = (char*)d_ws;
  // layout (bytes):
  //   [0,          50331648)  Xb   : bf16 query|key|value  [3][8192][1024]
  //   [50331648,   56623104)  Wqb  : bf16 w_qkv [3072][1024]
  //   [56623104,   58720256)  Wob  : bf16 w_out [1024][1024]
  //   [58720256,  109051904)  QKVb : bf16 [3][B][H][T][64]
  //   Xb region is dead after GEMM1; reuse: CTXb at +0 (16.8MB), Vtb at +16.8MB (16.8MB)
  unsigned short* Xb   = (unsigned short*)(ws);
  unsigned short* Wqb  = (unsigned short*)(ws + 50331648);
  unsigned short* Wob  = (unsigned short*)(ws + 56623104);
  unsigned short* QKVb = (unsigned short*)(ws + 58720256);
  unsigned short* CTXb = (unsigned short*)(ws);             // [B][T][E]
  unsigned short* Vtb  = (unsigned short*)(ws + 16777216);  // [B][H][64][T]

  cvt_kernel<<<2048, 256, 0, stream>>>((const float4*)q, (uint2*)Xb, 2097152);
  cvt_kernel<<<2048, 256, 0, stream>>>((const float4*)k, (uint2*)(Xb + 8388608), 2097152);
  cvt_kernel<<<2048, 256, 0, stream>>>((const float4*)v, (uint2*)(Xb + 16777216), 2097152);
  cvt_kernel<<<1024, 256, 0, stream>>>((const float4*)wqkv, (uint2*)Wqb, 786432);
  cvt_kernel<<<512, 256, 0, stream>>>((const float4*)wout, (uint2*)Wob, 262144);

  gemm_kernel<0><<<dim3(64, 24), 256, 0, stream>>>(Xb, Wqb, bqkv, QKVb, 1024);
  transpose_v<<<dim3(32, 64), 256, 0, stream>>>(QKVb + 16777216, Vtb);
  attn_kernel<<<dim3(32, 64), 256, 0, stream>>>(QKVb, QKVb + 8388608, Vtb, mask, CTXb);
  gemm_kernel<1><<<dim3(64, 8), 256, 0, stream>>>(CTXb, Wob, bout, d_out, 1024);
}